// Round 2
// baseline (488.286 us; speedup 1.0000x reference)
//
#include <hip/hip_runtime.h>

#define NNODES 50000

typedef __attribute__((ext_vector_type(8))) short s16x8;
typedef __attribute__((ext_vector_type(4))) float f32x4;
typedef __attribute__((ext_vector_type(2))) unsigned int u32x2;

__device__ __forceinline__ unsigned short f2bf(float f) {
  unsigned int u = __builtin_bit_cast(unsigned int, f);
  u += 0x7fffu + ((u >> 16) & 1u);
  return (unsigned short)(u >> 16);
}
__device__ __forceinline__ float bflo(unsigned int u) {
  return __builtin_bit_cast(float, u << 16);
}
__device__ __forceinline__ float bfhi(unsigned int u) {
  return __builtin_bit_cast(float, u & 0xffff0000u);
}

// ---------------- weight prep ----------------
__global__ void prep_w1t_k(const float* __restrict__ W1, unsigned short* __restrict__ w1t) {
  int i = blockIdx.x * 256 + threadIdx.x;          // 256*512 = 131072
  int nn = i >> 9, kk = i & 511;
  w1t[i] = f2bf(W1[kk * 256 + nn]);
}
__global__ void prep_w2t_k(const float* __restrict__ W2, unsigned short* __restrict__ w2t) {
  int i = blockIdx.x * 256 + threadIdx.x;          // 64*256 = 16384
  int nn = i >> 8, kk = i & 255;
  w2t[i] = (nn < 40) ? f2bf(W2[kk * 40 + nn]) : (unsigned short)0;
}

// ---------------- CSR build ----------------
__global__ void count_k(const int* __restrict__ dst, int* __restrict__ deg, int E) {
  int e = blockIdx.x * 256 + threadIdx.x;
  if (e < E) atomicAdd(&deg[dst[e]], 1);
}

__global__ void scan1_k(const int* __restrict__ deg, int* __restrict__ incl,
                        int* __restrict__ bsum, int n) {
  __shared__ int s[256];
  int t = threadIdx.x;
  int i = blockIdx.x * 256 + t;
  int v = (i < n) ? deg[i] : 0;
  s[t] = v; __syncthreads();
  for (int off = 1; off < 256; off <<= 1) {
    int xv = (t >= off) ? s[t - off] : 0;
    __syncthreads();
    s[t] += xv;
    __syncthreads();
  }
  if (i < n) incl[i] = s[t];
  if (t == 255) bsum[blockIdx.x] = s[255];
}

__global__ void scan2_k(int* __restrict__ bsum, int nb) {
  __shared__ int s[256];
  int t = threadIdx.x;
  int v = (t < nb) ? bsum[t] : 0;
  s[t] = v; __syncthreads();
  for (int off = 1; off < 256; off <<= 1) {
    int xv = (t >= off) ? s[t - off] : 0;
    __syncthreads();
    s[t] += xv;
    __syncthreads();
  }
  bsum[t] = s[t];
}

__global__ void scan3_k(const int* __restrict__ deg, const int* __restrict__ incl,
                        const int* __restrict__ bsum, int* __restrict__ rowptr,
                        int* __restrict__ cursor, int n, int E) {
  int i = blockIdx.x * 256 + threadIdx.x;
  if (i < n) {
    int add = (blockIdx.x > 0) ? bsum[blockIdx.x - 1] : 0;
    int excl = incl[i] - deg[i] + add;
    rowptr[i] = excl;
    cursor[i] = excl;
  }
  if (i == 0) rowptr[n] = E;
}

__global__ void scatter_k(const int* __restrict__ src, const int* __restrict__ dst,
                          const float* __restrict__ ew, int* __restrict__ cursor,
                          int* __restrict__ srcs, float* __restrict__ wsrt, int E) {
  int e = blockIdx.x * 256 + threadIdx.x;
  if (e < E) {
    int d = dst[e];
    int p = atomicAdd(&cursor[d], 1);
    srcs[p] = src[e];
    wsrt[p] = ew[e];
  }
}

// ---------------- GEMM1: h0 = bf16(x @ W1), [M,512]x[512,256] ----------------
__global__ __launch_bounds__(256) void gemm1_k(const float* __restrict__ x,
                                               const unsigned short* __restrict__ w1t,
                                               unsigned short* __restrict__ h0, int M) {
  __shared__ unsigned short sA[64][40];  // row stride 80B: 16B-aligned, breaks pow2 conflicts
  const int t = threadIdx.x;
  const int lane = t & 63;
  const int wv = t >> 6;
  const int l15 = lane & 15;
  const int lh = lane >> 4;
  const int bm0 = blockIdx.x * 64;
  const int arow = t >> 2;
  const int akc = (t & 3) << 3;

  f32x4 acc[4][4];
#pragma unroll
  for (int m = 0; m < 4; ++m)
#pragma unroll
    for (int n = 0; n < 4; ++n)
      acc[m][n] = (f32x4){0.f, 0.f, 0.f, 0.f};

  for (int k0 = 0; k0 < 512; k0 += 32) {
    __syncthreads();
    {
      int gr = bm0 + arow;
      s16x8 v;
      if (gr < M) {
        const float* px = x + (size_t)gr * 512 + k0 + akc;
#pragma unroll
        for (int j = 0; j < 8; ++j) v[j] = (short)f2bf(px[j]);
      } else {
#pragma unroll
        for (int j = 0; j < 8; ++j) v[j] = 0;
      }
      *(s16x8*)&sA[arow][akc] = v;
    }
    __syncthreads();
    s16x8 af[4];
#pragma unroll
    for (int m = 0; m < 4; ++m)
      af[m] = *(const s16x8*)&sA[m * 16 + l15][lh * 8];
#pragma unroll
    for (int n = 0; n < 4; ++n) {
      const int col = wv * 64 + n * 16 + l15;
      s16x8 bf = *(const s16x8*)&w1t[(size_t)col * 512 + k0 + lh * 8];
#pragma unroll
      for (int m = 0; m < 4; ++m)
        acc[m][n] = __builtin_amdgcn_mfma_f32_16x16x32_bf16(af[m], bf, acc[m][n], 0, 0, 0);
    }
  }
#pragma unroll
  for (int m = 0; m < 4; ++m) {
#pragma unroll
    for (int r = 0; r < 4; ++r) {
      int row = bm0 + m * 16 + lh * 4 + r;
      if (row < M) {
#pragma unroll
        for (int n = 0; n < 4; ++n) {
          int col = wv * 64 + n * 16 + l15;
          h0[(size_t)row * 256 + col] = f2bf(acc[m][n][r]);
        }
      }
    }
  }
}

// ---------------- spmm1: h1 = bf16(relu(segment_sum(w*h0[src]) + b1)) ----------------
__global__ __launch_bounds__(256) void spmm1_k(const unsigned short* __restrict__ h0,
                                               const int* __restrict__ rowptr,
                                               const int* __restrict__ srcs,
                                               const float* __restrict__ wsrt,
                                               const float* __restrict__ b1,
                                               unsigned short* __restrict__ h1, int N) {
  int d = blockIdx.x * 4 + (threadIdx.x >> 6);
  int lane = threadIdx.x & 63;
  if (d >= N) return;
  int beg = rowptr[d], end = rowptr[d + 1];
  float a0 = 0.f, a1 = 0.f, a2 = 0.f, a3 = 0.f;
  for (int e = beg; e < end; ++e) {
    int s = srcs[e];
    float w = wsrt[e];
    u32x2 v = *(const u32x2*)(h0 + (size_t)s * 256 + lane * 4);
    a0 += w * bflo(v[0]);
    a1 += w * bfhi(v[0]);
    a2 += w * bflo(v[1]);
    a3 += w * bfhi(v[1]);
  }
  f32x4 bb = *(const f32x4*)(b1 + lane * 4);
  float r0 = fmaxf(a0 + bb[0], 0.f);
  float r1 = fmaxf(a1 + bb[1], 0.f);
  float r2 = fmaxf(a2 + bb[2], 0.f);
  float r3 = fmaxf(a3 + bb[3], 0.f);
  u32x2 o;
  o[0] = (unsigned int)f2bf(r0) | ((unsigned int)f2bf(r1) << 16);
  o[1] = (unsigned int)f2bf(r2) | ((unsigned int)f2bf(r3) << 16);
  *(u32x2*)(h1 + (size_t)d * 256 + lane * 4) = o;
}

// ---------------- GEMM2: h2 = f32(h1 @ W2), [M,256]x[256,40] (N padded to 48) ----------------
__global__ __launch_bounds__(256) void gemm2_k(const unsigned short* __restrict__ h1,
                                               const unsigned short* __restrict__ w2t,
                                               float* __restrict__ h2, int M) {
  __shared__ unsigned short sA[64][40];
  const int t = threadIdx.x;
  const int lane = t & 63;
  const int wv = t >> 6;
  const int l15 = lane & 15;
  const int lh = lane >> 4;
  const int bm0 = blockIdx.x * 64;
  const int arow = t >> 2;
  const int akc = (t & 3) << 3;

  f32x4 acc[3];
#pragma unroll
  for (int n = 0; n < 3; ++n) acc[n] = (f32x4){0.f, 0.f, 0.f, 0.f};

  for (int k0 = 0; k0 < 256; k0 += 32) {
    __syncthreads();
    {
      int gr = bm0 + arow;
      s16x8 v;
      if (gr < M) {
        v = *(const s16x8*)(h1 + (size_t)gr * 256 + k0 + akc);
      } else {
#pragma unroll
        for (int j = 0; j < 8; ++j) v[j] = 0;
      }
      *(s16x8*)&sA[arow][akc] = v;
    }
    __syncthreads();
    s16x8 af = *(const s16x8*)&sA[wv * 16 + l15][lh * 8];
#pragma unroll
    for (int n = 0; n < 3; ++n) {
      s16x8 bf = *(const s16x8*)&w2t[(size_t)(n * 16 + l15) * 256 + k0 + lh * 8];
      acc[n] = __builtin_amdgcn_mfma_f32_16x16x32_bf16(af, bf, acc[n], 0, 0, 0);
    }
  }
#pragma unroll
  for (int n = 0; n < 3; ++n) {
#pragma unroll
    for (int r = 0; r < 4; ++r) {
      int row = bm0 + wv * 16 + lh * 4 + r;
      int col = n * 16 + l15;
      if (row < M && col < 40) h2[(size_t)row * 40 + col] = acc[n][r];
    }
  }
}

// ---------------- spmm2 + bias + log_softmax, fused ----------------
__global__ __launch_bounds__(256) void spmm2_k(const float* __restrict__ h2,
                                               const int* __restrict__ rowptr,
                                               const int* __restrict__ srcs,
                                               const float* __restrict__ wsrt,
                                               const float* __restrict__ b2,
                                               float* __restrict__ out, int N) {
  int d = blockIdx.x * 4 + (threadIdx.x >> 6);
  int lane = threadIdx.x & 63;
  if (d >= N) return;
  int beg = rowptr[d], end = rowptr[d + 1];
  bool act = lane < 40;
  float acc = 0.f;
  for (int e = beg; e < end; ++e) {
    int s = srcs[e];
    float w = wsrt[e];
    float hv = act ? h2[(size_t)s * 40 + lane] : 0.f;
    acc += w * hv;
  }
  float v = act ? (acc + b2[lane]) : -1e30f;
  float m = v;
#pragma unroll
  for (int off = 32; off; off >>= 1) m = fmaxf(m, __shfl_xor(m, off));
  float ex = act ? __expf(v - m) : 0.f;
  float sm = ex;
#pragma unroll
  for (int off = 32; off; off >>= 1) sm += __shfl_xor(sm, off);
  if (act) out[(size_t)d * 40 + lane] = v - m - __logf(sm);
}

// ---------------- launch ----------------
extern "C" void kernel_launch(void* const* d_in, const int* in_sizes, int n_in,
                              void* d_out, int out_size, void* d_ws, size_t ws_size,
                              hipStream_t stream) {
  const float* x = (const float*)d_in[0];
  const int* ei = (const int*)d_in[1];
  const float* ew = (const float*)d_in[2];
  const float* W1 = (const float*)d_in[3];
  const float* b1 = (const float*)d_in[4];
  const float* W2 = (const float*)d_in[5];
  const float* b2 = (const float*)d_in[6];
  float* out = (float*)d_out;

  const int N = NNODES;
  const int E = in_sizes[1] / 2;
  const int* src = ei;
  const int* dst = ei + E;

  char* p = (char*)d_ws;
  auto alloc = [&](size_t bytes) -> char* {
    char* r = p;
    p += (bytes + 255) & ~(size_t)255;
    return r;
  };
  unsigned short* h0   = (unsigned short*)alloc((size_t)N * 256 * 2);
  unsigned short* h1   = (unsigned short*)alloc((size_t)N * 256 * 2);
  float*          h2   = (float*)alloc((size_t)N * 40 * 4);
  unsigned short* w1t  = (unsigned short*)alloc(256 * 512 * 2);
  unsigned short* w2t  = (unsigned short*)alloc(64 * 256 * 2);
  int*            deg  = (int*)alloc((size_t)N * 4);
  int*            incl = (int*)alloc((size_t)N * 4);
  int*            rowptr = (int*)alloc((size_t)(N + 1) * 4);
  int*            cursor = (int*)alloc((size_t)N * 4);
  int*            bsum = (int*)alloc(256 * 4);
  int*            srcs = (int*)alloc((size_t)E * 4);
  float*          wsrt = (float*)alloc((size_t)E * 4);

  hipMemsetAsync(deg, 0, (size_t)N * 4, stream);

  prep_w1t_k<<<512, 256, 0, stream>>>(W1, w1t);
  prep_w2t_k<<<64, 256, 0, stream>>>(W2, w2t);

  int ebl = (E + 255) / 256;
  count_k<<<ebl, 256, 0, stream>>>(dst, deg, E);
  int nb = (N + 255) / 256;
  scan1_k<<<nb, 256, 0, stream>>>(deg, incl, bsum, N);
  scan2_k<<<1, 256, 0, stream>>>(bsum, nb);
  scan3_k<<<nb, 256, 0, stream>>>(deg, incl, bsum, rowptr, cursor, N, E);
  scatter_k<<<ebl, 256, 0, stream>>>(src, dst, ew, cursor, srcs, wsrt, E);

  gemm1_k<<<(N + 63) / 64, 256, 0, stream>>>(x, w1t, h0, N);
  spmm1_k<<<(N + 3) / 4, 256, 0, stream>>>(h0, rowptr, srcs, wsrt, b1, h1, N);
  gemm2_k<<<(N + 63) / 64, 256, 0, stream>>>(h1, w2t, h2, N);
  spmm2_k<<<(N + 3) / 4, 256, 0, stream>>>(h2, rowptr, srcs, wsrt, b2, out, N);
}

// Round 3
// 413.300 us; speedup vs baseline: 1.1814x; 1.1814x over previous
//
#include <hip/hip_runtime.h>

#define NNODES 50000

typedef __attribute__((ext_vector_type(8))) short s16x8;
typedef __attribute__((ext_vector_type(4))) float f32x4;
typedef __attribute__((ext_vector_type(2))) unsigned int u32x2;
typedef __attribute__((ext_vector_type(4))) unsigned int u32x4;

__device__ __forceinline__ unsigned short f2bf(float f) {
  unsigned int u = __builtin_bit_cast(unsigned int, f);
  u += 0x7fffu + ((u >> 16) & 1u);
  return (unsigned short)(u >> 16);
}
__device__ __forceinline__ float bflo(unsigned int u) {
  return __builtin_bit_cast(float, u << 16);
}
__device__ __forceinline__ float bfhi(unsigned int u) {
  return __builtin_bit_cast(float, u & 0xffff0000u);
}

// ---------------- weight prep ----------------
__global__ void prep_w1t_k(const float* __restrict__ W1, unsigned short* __restrict__ w1t) {
  int i = blockIdx.x * 256 + threadIdx.x;          // 256*512 = 131072
  int nn = i >> 9, kk = i & 511;
  w1t[i] = f2bf(W1[kk * 256 + nn]);
}
__global__ void prep_w2t_k(const float* __restrict__ W2, unsigned short* __restrict__ w2t) {
  int i = blockIdx.x * 256 + threadIdx.x;          // 64*256 = 16384
  int nn = i >> 8, kk = i & 255;
  w2t[i] = (nn < 40) ? f2bf(W2[kk * 40 + nn]) : (unsigned short)0;
}

// ---------------- CSR build ----------------
__global__ void count_k(const int* __restrict__ dst, int* __restrict__ deg, int E) {
  int e = blockIdx.x * 256 + threadIdx.x;
  if (e < E) atomicAdd(&deg[dst[e]], 1);
}

__global__ void scan1_k(const int* __restrict__ deg, int* __restrict__ incl,
                        int* __restrict__ bsum, int n) {
  __shared__ int s[256];
  int t = threadIdx.x;
  int i = blockIdx.x * 256 + t;
  int v = (i < n) ? deg[i] : 0;
  s[t] = v; __syncthreads();
  for (int off = 1; off < 256; off <<= 1) {
    int xv = (t >= off) ? s[t - off] : 0;
    __syncthreads();
    s[t] += xv;
    __syncthreads();
  }
  if (i < n) incl[i] = s[t];
  if (t == 255) bsum[blockIdx.x] = s[255];
}

__global__ void scan2_k(int* __restrict__ bsum, int nb) {
  __shared__ int s[256];
  int t = threadIdx.x;
  int v = (t < nb) ? bsum[t] : 0;
  s[t] = v; __syncthreads();
  for (int off = 1; off < 256; off <<= 1) {
    int xv = (t >= off) ? s[t - off] : 0;
    __syncthreads();
    s[t] += xv;
    __syncthreads();
  }
  bsum[t] = s[t];
}

__global__ void scan3_k(const int* __restrict__ deg, const int* __restrict__ incl,
                        const int* __restrict__ bsum, int* __restrict__ rowptr,
                        int* __restrict__ cursor, int n, int E) {
  int i = blockIdx.x * 256 + threadIdx.x;
  if (i < n) {
    int add = (blockIdx.x > 0) ? bsum[blockIdx.x - 1] : 0;
    int excl = incl[i] - deg[i] + add;
    rowptr[i] = excl;
    cursor[i] = excl;
  }
  if (i == 0) rowptr[n] = E;
}

__global__ void scatter_k(const int* __restrict__ src, const int* __restrict__ dst,
                          const float* __restrict__ ew, int* __restrict__ cursor,
                          int* __restrict__ srcs, float* __restrict__ wsrt, int E) {
  int e = blockIdx.x * 256 + threadIdx.x;
  if (e < E) {
    int d = dst[e];
    int p = atomicAdd(&cursor[d], 1);
    srcs[p] = src[e];
    wsrt[p] = ew[e];
  }
}

// ---------------- GEMM1: h0 = bf16(x @ W1), [M,512]x[512,256] ----------------
__global__ __launch_bounds__(256) void gemm1_k(const float* __restrict__ x,
                                               const unsigned short* __restrict__ w1t,
                                               unsigned short* __restrict__ h0, int M) {
  __shared__ unsigned short sA[64][40];  // row stride 80B: 16B-aligned, breaks pow2 conflicts
  const int t = threadIdx.x;
  const int lane = t & 63;
  const int wv = t >> 6;
  const int l15 = lane & 15;
  const int lh = lane >> 4;
  const int bm0 = blockIdx.x * 64;
  const int arow = t >> 2;
  const int akc = (t & 3) << 3;

  f32x4 acc[4][4];
#pragma unroll
  for (int m = 0; m < 4; ++m)
#pragma unroll
    for (int n = 0; n < 4; ++n)
      acc[m][n] = (f32x4){0.f, 0.f, 0.f, 0.f};

  for (int k0 = 0; k0 < 512; k0 += 32) {
    __syncthreads();
    {
      int gr = bm0 + arow;
      s16x8 v;
      if (gr < M) {
        const float* px = x + (size_t)gr * 512 + k0 + akc;
#pragma unroll
        for (int j = 0; j < 8; ++j) v[j] = (short)f2bf(px[j]);
      } else {
#pragma unroll
        for (int j = 0; j < 8; ++j) v[j] = 0;
      }
      *(s16x8*)&sA[arow][akc] = v;
    }
    __syncthreads();
    s16x8 af[4];
#pragma unroll
    for (int m = 0; m < 4; ++m)
      af[m] = *(const s16x8*)&sA[m * 16 + l15][lh * 8];
#pragma unroll
    for (int n = 0; n < 4; ++n) {
      const int col = wv * 64 + n * 16 + l15;
      s16x8 bf = *(const s16x8*)&w1t[(size_t)col * 512 + k0 + lh * 8];
#pragma unroll
      for (int m = 0; m < 4; ++m)
        acc[m][n] = __builtin_amdgcn_mfma_f32_16x16x32_bf16(af[m], bf, acc[m][n], 0, 0, 0);
    }
  }
#pragma unroll
  for (int m = 0; m < 4; ++m) {
#pragma unroll
    for (int r = 0; r < 4; ++r) {
      int row = bm0 + m * 16 + lh * 4 + r;
      if (row < M) {
#pragma unroll
        for (int n = 0; n < 4; ++n) {
          int col = wv * 64 + n * 16 + l15;
          h0[(size_t)row * 256 + col] = f2bf(acc[m][n][r]);
        }
      }
    }
  }
}

// ---------------- spmm1 v2: half-wave per edge, 16B/lane gather, ILP x2 ----------------
// h1 = bf16(relu(segment_sum(w*h0[src]) + b1))
__global__ __launch_bounds__(256) void spmm1_k(const unsigned short* __restrict__ h0,
                                               const int* __restrict__ rowptr,
                                               const int* __restrict__ srcs,
                                               const float* __restrict__ wsrt,
                                               const float* __restrict__ b1,
                                               unsigned short* __restrict__ h1, int N) {
  int d = blockIdx.x * 4 + (threadIdx.x >> 6);
  int lane = threadIdx.x & 63;
  if (d >= N) return;
  const int half = lane >> 5;        // 0 or 1: which edge of the pair
  const int sl = lane & 31;          // 16B slot within the 512B row
  int beg = rowptr[d], end = rowptr[d + 1];

  float acc[8];
#pragma unroll
  for (int j = 0; j < 8; ++j) acc[j] = 0.f;

  int e = beg;
  // 2 pairs (4 edges) per iteration: 2 independent 16B loads in flight per lane
  for (; e + 3 < end; e += 4) {
    int s0 = srcs[e + half];
    int s1 = srcs[e + 2 + half];
    float w0 = wsrt[e + half];
    float w1 = wsrt[e + 2 + half];
    u32x4 v0 = *(const u32x4*)(h0 + (size_t)s0 * 256 + sl * 8);
    u32x4 v1 = *(const u32x4*)(h0 + (size_t)s1 * 256 + sl * 8);
#pragma unroll
    for (int q = 0; q < 4; ++q) {
      acc[2 * q]     += w0 * bflo(v0[q]);
      acc[2 * q + 1] += w0 * bfhi(v0[q]);
    }
#pragma unroll
    for (int q = 0; q < 4; ++q) {
      acc[2 * q]     += w1 * bflo(v1[q]);
      acc[2 * q + 1] += w1 * bfhi(v1[q]);
    }
  }
  // one pair
  for (; e + 1 < end; e += 2) {
    int s0 = srcs[e + half];
    float w0 = wsrt[e + half];
    u32x4 v0 = *(const u32x4*)(h0 + (size_t)s0 * 256 + sl * 8);
#pragma unroll
    for (int q = 0; q < 4; ++q) {
      acc[2 * q]     += w0 * bflo(v0[q]);
      acc[2 * q + 1] += w0 * bfhi(v0[q]);
    }
  }
  // odd tail: half 0 only
  if (e < end && half == 0) {
    int s0 = srcs[e];
    float w0 = wsrt[e];
    u32x4 v0 = *(const u32x4*)(h0 + (size_t)s0 * 256 + sl * 8);
#pragma unroll
    for (int q = 0; q < 4; ++q) {
      acc[2 * q]     += w0 * bflo(v0[q]);
      acc[2 * q + 1] += w0 * bfhi(v0[q]);
    }
  }
  // merge the two halves
#pragma unroll
  for (int j = 0; j < 8; ++j) acc[j] += __shfl_xor(acc[j], 32);

  if (half == 0) {
    u32x4 o;
#pragma unroll
    for (int q = 0; q < 4; ++q) {
      float r0 = fmaxf(acc[2 * q]     + b1[sl * 8 + 2 * q],     0.f);
      float r1 = fmaxf(acc[2 * q + 1] + b1[sl * 8 + 2 * q + 1], 0.f);
      o[q] = (unsigned int)f2bf(r0) | ((unsigned int)f2bf(r1) << 16);
    }
    *(u32x4*)(h1 + (size_t)d * 256 + sl * 8) = o;
  }
}

// ---------------- GEMM2: h2 = f32(h1 @ W2), [M,256]x[256,40] (N padded to 48) ----------------
__global__ __launch_bounds__(256) void gemm2_k(const unsigned short* __restrict__ h1,
                                               const unsigned short* __restrict__ w2t,
                                               float* __restrict__ h2, int M) {
  __shared__ unsigned short sA[64][40];
  const int t = threadIdx.x;
  const int lane = t & 63;
  const int wv = t >> 6;
  const int l15 = lane & 15;
  const int lh = lane >> 4;
  const int bm0 = blockIdx.x * 64;
  const int arow = t >> 2;
  const int akc = (t & 3) << 3;

  f32x4 acc[3];
#pragma unroll
  for (int n = 0; n < 3; ++n) acc[n] = (f32x4){0.f, 0.f, 0.f, 0.f};

  for (int k0 = 0; k0 < 256; k0 += 32) {
    __syncthreads();
    {
      int gr = bm0 + arow;
      s16x8 v;
      if (gr < M) {
        v = *(const s16x8*)(h1 + (size_t)gr * 256 + k0 + akc);
      } else {
#pragma unroll
        for (int j = 0; j < 8; ++j) v[j] = 0;
      }
      *(s16x8*)&sA[arow][akc] = v;
    }
    __syncthreads();
    s16x8 af = *(const s16x8*)&sA[wv * 16 + l15][lh * 8];
#pragma unroll
    for (int n = 0; n < 3; ++n) {
      s16x8 bf = *(const s16x8*)&w2t[(size_t)(n * 16 + l15) * 256 + k0 + lh * 8];
      acc[n] = __builtin_amdgcn_mfma_f32_16x16x32_bf16(af, bf, acc[n], 0, 0, 0);
    }
  }
#pragma unroll
  for (int n = 0; n < 3; ++n) {
#pragma unroll
    for (int r = 0; r < 4; ++r) {
      int row = bm0 + wv * 16 + lh * 4 + r;
      int col = n * 16 + l15;
      if (row < M && col < 40) h2[(size_t)row * 40 + col] = acc[n][r];
    }
  }
}

// ---------------- spmm2 + bias + log_softmax, fused (ILP x4) ----------------
__global__ __launch_bounds__(256) void spmm2_k(const float* __restrict__ h2,
                                               const int* __restrict__ rowptr,
                                               const int* __restrict__ srcs,
                                               const float* __restrict__ wsrt,
                                               const float* __restrict__ b2,
                                               float* __restrict__ out, int N) {
  int d = blockIdx.x * 4 + (threadIdx.x >> 6);
  int lane = threadIdx.x & 63;
  if (d >= N) return;
  int beg = rowptr[d], end = rowptr[d + 1];
  bool act = lane < 40;
  int lx = act ? lane : 0;
  float acc = 0.f;
  int e = beg;
  for (; e + 3 < end; e += 4) {
    int s0 = srcs[e],     s1 = srcs[e + 1];
    int s2 = srcs[e + 2], s3 = srcs[e + 3];
    float w0 = wsrt[e],     w1 = wsrt[e + 1];
    float w2 = wsrt[e + 2], w3 = wsrt[e + 3];
    float hv0 = h2[(size_t)s0 * 40 + lx];
    float hv1 = h2[(size_t)s1 * 40 + lx];
    float hv2 = h2[(size_t)s2 * 40 + lx];
    float hv3 = h2[(size_t)s3 * 40 + lx];
    acc += w0 * hv0 + w1 * hv1 + w2 * hv2 + w3 * hv3;
  }
  for (; e < end; ++e) {
    int s = srcs[e];
    float w = wsrt[e];
    acc += w * h2[(size_t)s * 40 + lx];
  }
  float v = act ? (acc + b2[lane]) : -1e30f;
  float m = v;
#pragma unroll
  for (int off = 32; off; off >>= 1) m = fmaxf(m, __shfl_xor(m, off));
  float ex = act ? __expf(v - m) : 0.f;
  float sm = ex;
#pragma unroll
  for (int off = 32; off; off >>= 1) sm += __shfl_xor(sm, off);
  if (act) out[(size_t)d * 40 + lane] = v - m - __logf(sm);
}

// ---------------- launch ----------------
extern "C" void kernel_launch(void* const* d_in, const int* in_sizes, int n_in,
                              void* d_out, int out_size, void* d_ws, size_t ws_size,
                              hipStream_t stream) {
  const float* x = (const float*)d_in[0];
  const int* ei = (const int*)d_in[1];
  const float* ew = (const float*)d_in[2];
  const float* W1 = (const float*)d_in[3];
  const float* b1 = (const float*)d_in[4];
  const float* W2 = (const float*)d_in[5];
  const float* b2 = (const float*)d_in[6];
  float* out = (float*)d_out;

  const int N = NNODES;
  const int E = in_sizes[1] / 2;
  const int* src = ei;
  const int* dst = ei + E;

  char* p = (char*)d_ws;
  auto alloc = [&](size_t bytes) -> char* {
    char* r = p;
    p += (bytes + 255) & ~(size_t)255;
    return r;
  };
  unsigned short* h0   = (unsigned short*)alloc((size_t)N * 256 * 2);
  unsigned short* h1   = (unsigned short*)alloc((size_t)N * 256 * 2);
  float*          h2   = (float*)alloc((size_t)N * 40 * 4);
  unsigned short* w1t  = (unsigned short*)alloc(256 * 512 * 2);
  unsigned short* w2t  = (unsigned short*)alloc(64 * 256 * 2);
  int*            deg  = (int*)alloc((size_t)N * 4);
  int*            incl = (int*)alloc((size_t)N * 4);
  int*            rowptr = (int*)alloc((size_t)(N + 1) * 4);
  int*            cursor = (int*)alloc((size_t)N * 4);
  int*            bsum = (int*)alloc(256 * 4);
  int*            srcs = (int*)alloc((size_t)E * 4);
  float*          wsrt = (float*)alloc((size_t)E * 4);

  hipMemsetAsync(deg, 0, (size_t)N * 4, stream);

  prep_w1t_k<<<512, 256, 0, stream>>>(W1, w1t);
  prep_w2t_k<<<64, 256, 0, stream>>>(W2, w2t);

  int ebl = (E + 255) / 256;
  count_k<<<ebl, 256, 0, stream>>>(dst, deg, E);
  int nb = (N + 255) / 256;
  scan1_k<<<nb, 256, 0, stream>>>(deg, incl, bsum, N);
  scan2_k<<<1, 256, 0, stream>>>(bsum, nb);
  scan3_k<<<nb, 256, 0, stream>>>(deg, incl, bsum, rowptr, cursor, N, E);
  scatter_k<<<ebl, 256, 0, stream>>>(src, dst, ew, cursor, srcs, wsrt, E);

  gemm1_k<<<(N + 63) / 64, 256, 0, stream>>>(x, w1t, h0, N);
  spmm1_k<<<(N + 3) / 4, 256, 0, stream>>>(h0, rowptr, srcs, wsrt, b1, h1, N);
  gemm2_k<<<(N + 63) / 64, 256, 0, stream>>>(h1, w2t, h2, N);
  spmm2_k<<<(N + 3) / 4, 256, 0, stream>>>(h2, rowptr, srcs, wsrt, b2, out, N);
}

// Round 12
// 407.787 us; speedup vs baseline: 1.1974x; 1.0135x over previous
//
#include <hip/hip_runtime.h>

#define NNODES 50000

typedef __attribute__((ext_vector_type(8))) short s16x8;
typedef __attribute__((ext_vector_type(4))) float f32x4;
typedef __attribute__((ext_vector_type(2))) unsigned int u32x2;
typedef __attribute__((ext_vector_type(4))) unsigned int u32x4;

__device__ __forceinline__ unsigned short f2bf(float f) {
  unsigned int u = __builtin_bit_cast(unsigned int, f);
  u += 0x7fffu + ((u >> 16) & 1u);
  return (unsigned short)(u >> 16);
}
__device__ __forceinline__ float bflo(unsigned int u) {
  return __builtin_bit_cast(float, u << 16);
}
__device__ __forceinline__ float bfhi(unsigned int u) {
  return __builtin_bit_cast(float, u & 0xffff0000u);
}

// ---------------- x -> bf16 (padded to 50048 rows) ----------------
__global__ void prep_xbf_k(const float* __restrict__ x, unsigned short* __restrict__ xb, int M) {
  int i = blockIdx.x * 256 + threadIdx.x;  // one thread per 8 elements
  int row = i >> 6;                        // 64 chunks of 8 per 512-wide row
  s16x8 v;
  if (row < M) {
    const float* px = x + (size_t)i * 8;
    f32x4 a = *(const f32x4*)px;
    f32x4 b = *(const f32x4*)(px + 4);
    v[0] = (short)f2bf(a[0]); v[1] = (short)f2bf(a[1]);
    v[2] = (short)f2bf(a[2]); v[3] = (short)f2bf(a[3]);
    v[4] = (short)f2bf(b[0]); v[5] = (short)f2bf(b[1]);
    v[6] = (short)f2bf(b[2]); v[7] = (short)f2bf(b[3]);
  } else {
#pragma unroll
    for (int j = 0; j < 8; ++j) v[j] = 0;
  }
  *(s16x8*)(xb + (size_t)i * 8) = v;
}

// ---------------- weight prep ----------------
__global__ void prep_w1t_k(const float* __restrict__ W1, unsigned short* __restrict__ w1t) {
  int i = blockIdx.x * 256 + threadIdx.x;          // 256*512 = 131072
  int nn = i >> 9, kk = i & 511;
  w1t[i] = f2bf(W1[kk * 256 + nn]);
}
__global__ void prep_w2t_k(const float* __restrict__ W2, unsigned short* __restrict__ w2t) {
  int i = blockIdx.x * 256 + threadIdx.x;          // 64*256 = 16384
  int nn = i >> 8, kk = i & 255;
  w2t[i] = (nn < 40) ? f2bf(W2[kk * 40 + nn]) : (unsigned short)0;
}

// ---------------- CSR build ----------------
__global__ void count_k(const int* __restrict__ dst, int* __restrict__ deg, int E) {
  int e = blockIdx.x * 256 + threadIdx.x;
  if (e < E) atomicAdd(&deg[dst[e]], 1);
}

__global__ void scan1_k(const int* __restrict__ deg, int* __restrict__ incl,
                        int* __restrict__ bsum, int n) {
  __shared__ int s[256];
  int t = threadIdx.x;
  int i = blockIdx.x * 256 + t;
  int v = (i < n) ? deg[i] : 0;
  s[t] = v; __syncthreads();
  for (int off = 1; off < 256; off <<= 1) {
    int xv = (t >= off) ? s[t - off] : 0;
    __syncthreads();
    s[t] += xv;
    __syncthreads();
  }
  if (i < n) incl[i] = s[t];
  if (t == 255) bsum[blockIdx.x] = s[255];
}

__global__ void scan2_k(int* __restrict__ bsum, int nb) {
  __shared__ int s[256];
  int t = threadIdx.x;
  int v = (t < nb) ? bsum[t] : 0;
  s[t] = v; __syncthreads();
  for (int off = 1; off < 256; off <<= 1) {
    int xv = (t >= off) ? s[t - off] : 0;
    __syncthreads();
    s[t] += xv;
    __syncthreads();
  }
  bsum[t] = s[t];
}

__global__ void scan3_k(const int* __restrict__ deg, const int* __restrict__ incl,
                        const int* __restrict__ bsum, int* __restrict__ rowptr,
                        int* __restrict__ cursor, int n, int E) {
  int i = blockIdx.x * 256 + threadIdx.x;
  if (i < n) {
    int add = (blockIdx.x > 0) ? bsum[blockIdx.x - 1] : 0;
    int excl = incl[i] - deg[i] + add;
    rowptr[i] = excl;
    cursor[i] = excl;
  }
  if (i == 0) rowptr[n] = E;
}

__global__ void scatter_k(const int* __restrict__ src, const int* __restrict__ dst,
                          const float* __restrict__ ew, int* __restrict__ cursor,
                          int* __restrict__ srcs, float* __restrict__ wsrt, int E) {
  int e = blockIdx.x * 256 + threadIdx.x;
  if (e < E) {
    int d = dst[e];
    int p = atomicAdd(&cursor[d], 1);
    srcs[p] = src[e];
    wsrt[p] = ew[e];
  }
}

// ---------------- GEMM1 v2 (m97 structure): h0 = bf16(xb @ W1) ----------------
// BM=128, BN=128, BK=32; 4 waves, each a 64x64 sub-tile; A/B via global_load_lds(16B).
__global__ __launch_bounds__(256) void gemm1_k(const unsigned short* __restrict__ xb,
                                               const unsigned short* __restrict__ w1t,
                                               unsigned short* __restrict__ h0, int M) {
  __shared__ unsigned short sA[128 * 32];  // row-major [row][32k], 64B rows
  __shared__ unsigned short sB[128 * 32];  // [col][32k]
  const int t = threadIdx.x;
  const int lane = t & 63;
  const int wv = t >> 6;
  const int l15 = lane & 15;
  const int lh = lane >> 4;
  const int wr = wv >> 1;
  const int wc = wv & 1;
  const int rb = blockIdx.x >> 1;
  const int cb = blockIdx.x & 1;
  const int bm0 = rb * 128;
  const int bn0 = cb * 128;

  f32x4 acc[4][4];
#pragma unroll
  for (int m = 0; m < 4; ++m)
#pragma unroll
    for (int n = 0; n < 4; ++n)
      acc[m][n] = (f32x4){0.f, 0.f, 0.f, 0.f};

  for (int k0 = 0; k0 < 512; k0 += 32) {
    __syncthreads();  // previous iter's fragment reads done before overwrite
#pragma unroll
    for (int j = 0; j < 2; ++j) {
      int chunk = (wv * 2 + j) * 64 + lane;   // 0..511 (16B units)
      int row = chunk >> 2;
      int kc = (chunk & 3) << 3;
      const unsigned short* ga = xb + (size_t)(bm0 + row) * 512 + k0 + kc;
      const unsigned short* gb = w1t + (size_t)(bn0 + row) * 512 + k0 + kc;
      __builtin_amdgcn_global_load_lds(
          (const __attribute__((address_space(1))) unsigned int*)ga,
          (__attribute__((address_space(3))) unsigned int*)(sA + (wv * 2 + j) * 512), 16, 0, 0);
      __builtin_amdgcn_global_load_lds(
          (const __attribute__((address_space(1))) unsigned int*)gb,
          (__attribute__((address_space(3))) unsigned int*)(sB + (wv * 2 + j) * 512), 16, 0, 0);
    }
    __syncthreads();  // compiler drains vmcnt(0) before barrier

    s16x8 af[4], bfr[4];
#pragma unroll
    for (int m = 0; m < 4; ++m)
      af[m] = *(const s16x8*)(sA + (wr * 64 + m * 16 + l15) * 32 + lh * 8);
#pragma unroll
    for (int n = 0; n < 4; ++n)
      bfr[n] = *(const s16x8*)(sB + (wc * 64 + n * 16 + l15) * 32 + lh * 8);
#pragma unroll
    for (int n = 0; n < 4; ++n)
#pragma unroll
      for (int m = 0; m < 4; ++m)
        acc[m][n] = __builtin_amdgcn_mfma_f32_16x16x32_bf16(af[m], bfr[n], acc[m][n], 0, 0, 0);
  }

#pragma unroll
  for (int m = 0; m < 4; ++m) {
#pragma unroll
    for (int r = 0; r < 4; ++r) {
      int row = bm0 + wr * 64 + m * 16 + lh * 4 + r;
      if (row < M) {
#pragma unroll
        for (int n = 0; n < 4; ++n) {
          int col = bn0 + wc * 64 + n * 16 + l15;
          h0[(size_t)row * 256 + col] = f2bf(acc[m][n][r]);
        }
      }
    }
  }
}

// ---------------- spmm1: half-wave per edge, 16B/lane gather, ILP x2 ----------------
__global__ __launch_bounds__(256) void spmm1_k(const unsigned short* __restrict__ h0,
                                               const int* __restrict__ rowptr,
                                               const int* __restrict__ srcs,
                                               const float* __restrict__ wsrt,
                                               const float* __restrict__ b1,
                                               unsigned short* __restrict__ h1, int N) {
  int d = blockIdx.x * 4 + (threadIdx.x >> 6);
  int lane = threadIdx.x & 63;
  if (d >= N) return;
  const int half = lane >> 5;
  const int sl = lane & 31;
  int beg = rowptr[d], end = rowptr[d + 1];

  float acc[8];
#pragma unroll
  for (int j = 0; j < 8; ++j) acc[j] = 0.f;

  int e = beg;
  for (; e + 3 < end; e += 4) {
    int s0 = srcs[e + half];
    int s1 = srcs[e + 2 + half];
    float w0 = wsrt[e + half];
    float w1 = wsrt[e + 2 + half];
    u32x4 v0 = *(const u32x4*)(h0 + (size_t)s0 * 256 + sl * 8);
    u32x4 v1 = *(const u32x4*)(h0 + (size_t)s1 * 256 + sl * 8);
#pragma unroll
    for (int q = 0; q < 4; ++q) {
      acc[2 * q]     += w0 * bflo(v0[q]);
      acc[2 * q + 1] += w0 * bfhi(v0[q]);
    }
#pragma unroll
    for (int q = 0; q < 4; ++q) {
      acc[2 * q]     += w1 * bflo(v1[q]);
      acc[2 * q + 1] += w1 * bfhi(v1[q]);
    }
  }
  for (; e + 1 < end; e += 2) {
    int s0 = srcs[e + half];
    float w0 = wsrt[e + half];
    u32x4 v0 = *(const u32x4*)(h0 + (size_t)s0 * 256 + sl * 8);
#pragma unroll
    for (int q = 0; q < 4; ++q) {
      acc[2 * q]     += w0 * bflo(v0[q]);
      acc[2 * q + 1] += w0 * bfhi(v0[q]);
    }
  }
  if (e < end && half == 0) {
    int s0 = srcs[e];
    float w0 = wsrt[e];
    u32x4 v0 = *(const u32x4*)(h0 + (size_t)s0 * 256 + sl * 8);
#pragma unroll
    for (int q = 0; q < 4; ++q) {
      acc[2 * q]     += w0 * bflo(v0[q]);
      acc[2 * q + 1] += w0 * bfhi(v0[q]);
    }
  }
#pragma unroll
  for (int j = 0; j < 8; ++j) acc[j] += __shfl_xor(acc[j], 32);

  if (half == 0) {
    u32x4 o;
#pragma unroll
    for (int q = 0; q < 4; ++q) {
      float r0 = fmaxf(acc[2 * q]     + b1[sl * 8 + 2 * q],     0.f);
      float r1 = fmaxf(acc[2 * q + 1] + b1[sl * 8 + 2 * q + 1], 0.f);
      o[q] = (unsigned int)f2bf(r0) | ((unsigned int)f2bf(r1) << 16);
    }
    *(u32x4*)(h1 + (size_t)d * 256 + sl * 8) = o;
  }
}

// ---------------- GEMM2: h2 = f32(h1 @ W2), [M,256]x[256,40] ----------------
__global__ __launch_bounds__(256) void gemm2_k(const unsigned short* __restrict__ h1,
                                               const unsigned short* __restrict__ w2t,
                                               float* __restrict__ h2, int M) {
  __shared__ unsigned short sA[64][40];
  const int t = threadIdx.x;
  const int lane = t & 63;
  const int wv = t >> 6;
  const int l15 = lane & 15;
  const int lh = lane >> 4;
  const int bm0 = blockIdx.x * 64;
  const int arow = t >> 2;
  const int akc = (t & 3) << 3;

  f32x4 acc[3];
#pragma unroll
  for (int n = 0; n < 3; ++n) acc[n] = (f32x4){0.f, 0.f, 0.f, 0.f};

  for (int k0 = 0; k0 < 256; k0 += 32) {
    __syncthreads();
    {
      int gr = bm0 + arow;
      s16x8 v;
      if (gr < M) {
        v = *(const s16x8*)(h1 + (size_t)gr * 256 + k0 + akc);
      } else {
#pragma unroll
        for (int j = 0; j < 8; ++j) v[j] = 0;
      }
      *(s16x8*)&sA[arow][akc] = v;
    }
    __syncthreads();
    s16x8 af = *(const s16x8*)&sA[wv * 16 + l15][lh * 8];
#pragma unroll
    for (int n = 0; n < 3; ++n) {
      s16x8 bf = *(const s16x8*)&w2t[(size_t)(n * 16 + l15) * 256 + k0 + lh * 8];
      acc[n] = __builtin_amdgcn_mfma_f32_16x16x32_bf16(af, bf, acc[n], 0, 0, 0);
    }
  }
#pragma unroll
  for (int n = 0; n < 3; ++n) {
#pragma unroll
    for (int r = 0; r < 4; ++r) {
      int row = bm0 + wv * 16 + lh * 4 + r;
      int col = n * 16 + l15;
      if (row < M && col < 40) h2[(size_t)row * 40 + col] = acc[n][r];
    }
  }
}

// ---------------- spmm2 + bias + log_softmax, fused (ILP x4) ----------------
__global__ __launch_bounds__(256) void spmm2_k(const float* __restrict__ h2,
                                               const int* __restrict__ rowptr,
                                               const int* __restrict__ srcs,
                                               const float* __restrict__ wsrt,
                                               const float* __restrict__ b2,
                                               float* __restrict__ out, int N) {
  int d = blockIdx.x * 4 + (threadIdx.x >> 6);
  int lane = threadIdx.x & 63;
  if (d >= N) return;
  int beg = rowptr[d], end = rowptr[d + 1];
  bool act = lane < 40;
  int lx = act ? lane : 0;
  float acc = 0.f;
  int e = beg;
  for (; e + 3 < end; e += 4) {
    int s0 = srcs[e],     s1 = srcs[e + 1];
    int s2 = srcs[e + 2], s3 = srcs[e + 3];
    float w0 = wsrt[e],     w1 = wsrt[e + 1];
    float w2 = wsrt[e + 2], w3 = wsrt[e + 3];
    float hv0 = h2[(size_t)s0 * 40 + lx];
    float hv1 = h2[(size_t)s1 * 40 + lx];
    float hv2 = h2[(size_t)s2 * 40 + lx];
    float hv3 = h2[(size_t)s3 * 40 + lx];
    acc += w0 * hv0 + w1 * hv1 + w2 * hv2 + w3 * hv3;
  }
  for (; e < end; ++e) {
    int s = srcs[e];
    float w = wsrt[e];
    acc += w * h2[(size_t)s * 40 + lx];
  }
  float v = act ? (acc + b2[lane]) : -1e30f;
  float m = v;
#pragma unroll
  for (int off = 32; off; off >>= 1) m = fmaxf(m, __shfl_xor(m, off));
  float ex = act ? __expf(v - m) : 0.f;
  float sm = ex;
#pragma unroll
  for (int off = 32; off; off >>= 1) sm += __shfl_xor(sm, off);
  if (act) out[(size_t)d * 40 + lane] = v - m - __logf(sm);
}

// ---------------- launch ----------------
extern "C" void kernel_launch(void* const* d_in, const int* in_sizes, int n_in,
                              void* d_out, int out_size, void* d_ws, size_t ws_size,
                              hipStream_t stream) {
  const float* x = (const float*)d_in[0];
  const int* ei = (const int*)d_in[1];
  const float* ew = (const float*)d_in[2];
  const float* W1 = (const float*)d_in[3];
  const float* b1 = (const float*)d_in[4];
  const float* W2 = (const float*)d_in[5];
  const float* b2 = (const float*)d_in[6];
  float* out = (float*)d_out;

  const int N = NNODES;
  const int MP = 50048;            // N padded to 128
  const int E = in_sizes[1] / 2;
  const int* src = ei;
  const int* dst = ei + E;

  char* p = (char*)d_ws;
  auto alloc = [&](size_t bytes) -> char* {
    char* r = p;
    p += (bytes + 255) & ~(size_t)255;
    return r;
  };
  unsigned short* xbf  = (unsigned short*)alloc((size_t)MP * 512 * 2);  // h1 aliases this
  unsigned short* h0   = (unsigned short*)alloc((size_t)N * 256 * 2);
  float*          h2   = (float*)alloc((size_t)N * 40 * 4);
  unsigned short* w1t  = (unsigned short*)alloc(256 * 512 * 2);
  unsigned short* w2t  = (unsigned short*)alloc(64 * 256 * 2);
  int*            deg  = (int*)alloc((size_t)N * 4);
  int*            incl = (int*)alloc((size_t)N * 4);
  int*            rowptr = (int*)alloc((size_t)(N + 1) * 4);
  int*            cursor = (int*)alloc((size_t)N * 4);
  int*            bsum = (int*)alloc(256 * 4);
  int*            srcs = (int*)alloc((size_t)E * 4);
  float*          wsrt = (float*)alloc((size_t)E * 4);
  unsigned short* h1 = xbf;        // xbf dead after gemm1; h1 born at spmm1

  hipMemsetAsync(deg, 0, (size_t)N * 4, stream);

  prep_xbf_k<<<(MP * 64) / 256, 256, 0, stream>>>(x, xbf, N);
  prep_w1t_k<<<512, 256, 0, stream>>>(W1, w1t);
  prep_w2t_k<<<64, 256, 0, stream>>>(W2, w2t);

  int ebl = (E + 255) / 256;
  count_k<<<ebl, 256, 0, stream>>>(dst, deg, E);
  int nb = (N + 255) / 256;
  scan1_k<<<nb, 256, 0, stream>>>(deg, incl, bsum, N);
  scan2_k<<<1, 256, 0, stream>>>(bsum, nb);
  scan3_k<<<nb, 256, 0, stream>>>(deg, incl, bsum, rowptr, cursor, N, E);
  scatter_k<<<ebl, 256, 0, stream>>>(src, dst, ew, cursor, srcs, wsrt, E);

  gemm1_k<<<(MP / 128) * 2, 256, 0, stream>>>(xbf, w1t, h0, N);
  spmm1_k<<<(N + 3) / 4, 256, 0, stream>>>(h0, rowptr, srcs, wsrt, b1, h1, N);
  gemm2_k<<<(N + 63) / 64, 256, 0, stream>>>(h1, w2t, h2, N);
  spmm2_k<<<(N + 3) / 4, 256, 0, stream>>>(h2, rowptr, srcs, wsrt, b2, out, N);
}